// Round 1
// 217.322 us; speedup vs baseline: 1.0695x; 1.0695x over previous
//
#include <hip/hip_runtime.h>
#include <math.h>

// 20-qubit, 4-layer hardware-efficient ansatz statevector sim. B=4, DIM=2^20.
// Qubit q <-> global index bit (19-q).
//
// R12 = R11 (232us) + RZ-diagonal factorization for layers 1..3:
//  - Product of the 20 per-qubit RZ gates is DIAGONAL: D(g)=e^{i*alpha(g)},
//    alpha(g) = -0.5*sum(thz[l,:]) + sum_{p: bit p of g set} thz[l, 19-p].
//    Applied elementwise at pass_b load time (1 fast sincos + 4 FMA / element;
//    phase sum split into block-uniform (m), per-thread (t), compile-time (hi,e)
//    partial sums).
//  - Butterflies for layers 1..3 become pure RX: [[c,-is],[-is,c]] = 8 FMA/pair
//    instead of 16 (generic complex 2x2). pass_a VALU -28%, pass_b -12%.
//  - Layer 0 keeps the fused RX*RZ*H generic 16-FMA path (H not diagonal).
//  Ordering validity: D(l) commutes with nothing it precedes incorrectly --
//  pass_b(l) applies D before its RX gates; pass_a(l)'s RX (qubits 8..19) is
//  disjoint from pass_b's CX chain (qubits 0..7); chain order CNOT(0,1)..(18,19)
//  preserved across the pass split (identical to verified R8/R11 structure).
//
// Fusion: per layer per qubit, one butterfly. CNOT chain == gray gather, split:
//   pass B: CX targets global bits 12..18 (controls 13..19, tile-local)
//   pass A: CX targets global bits 0..11 (controls 1..11 local, control 12 = tile bit)
// Sequence: B0 A0 B1 A1 B2 A2 B3 A3 (separate kernels; HW handles coherence).
// State between passes: two bf16 planes in d_ws (8 MB each); first pass reads
// fp32 inputs; last pass writes fp32 real plane to d_out only (272 MB total,
// mostly L3-resident).
// LDS swizzle K(j)=j^(((j>>6)&0xF)<<2); all patterns <=2-way banked.

#define NQ 20

struct U2 { float r00,i00,r01,i01,r10,i10,r11,i11; };

__device__ __forceinline__ U2 make_u(const float* __restrict__ thx,
                                     const float* __restrict__ thz,
                                     int layer, int q, int withH) {
  float tx = 0.5f * thx[layer*NQ + q];
  float tz = 0.5f * thz[layer*NQ + q];
  float sx, cxv; __sincosf(tx, &sx, &cxv);
  float sz, cz;  __sincosf(tz, &sz, &cz);
  U2 u;
  u.r00 =  cxv*cz;  u.i00 = -cxv*sz;
  u.r01 =  sx*sz;   u.i01 = -sx*cz;
  u.r10 = -sx*sz;   u.i10 = -sx*cz;
  u.r11 =  cxv*cz;  u.i11 =  cxv*sz;
  if (withH) {
    const float r = 0.70710678118654752f;
    float a, b;
    a=u.r00; b=u.r01; u.r00=(a+b)*r; u.r01=(a-b)*r;
    a=u.i00; b=u.i01; u.i00=(a+b)*r; u.i01=(a-b)*r;
    a=u.r10; b=u.r11; u.r10=(a+b)*r; u.r11=(a-b)*r;
    a=u.i10; b=u.i11; u.i10=(a+b)*r; u.i11=(a-b)*r;
  }
  return u;
}

template <int ST>
__device__ __forceinline__ void bfly(float* re, float* im, const U2 u) {
#pragma unroll
  for (int s = 0; s < 16; ++s) {
    if ((s & ST) == 0) {
      const int s1 = s + ST;
      float ar = re[s], ai = im[s], br = re[s1], bi = im[s1];
      re[s]  = u.r00*ar - u.i00*ai + u.r01*br - u.i01*bi;
      im[s]  = u.r00*ai + u.i00*ar + u.r01*bi + u.i01*br;
      re[s1] = u.r10*ar - u.i10*ai + u.r11*br - u.i11*bi;
      im[s1] = u.r10*ai + u.i10*ar + u.r11*bi + u.i11*br;
    }
  }
}

// Pure RX butterfly: U = [[c, -i*s], [-i*s, c]] -> 8 FMA per pair.
template <int ST>
__device__ __forceinline__ void bfly_rx(float* re, float* im, float c, float s) {
#pragma unroll
  for (int k = 0; k < 16; ++k) {
    if ((k & ST) == 0) {
      const int k1 = k + ST;
      float ar = re[k], ai = im[k], br = re[k1], bi = im[k1];
      re[k]  = c*ar + s*bi;
      im[k]  = c*ai - s*br;
      re[k1] = c*br + s*ai;
      im[k1] = c*bi - s*ar;
    }
  }
}

template <int RXONLY, int ST>
__device__ __forceinline__ void gate(float* re, float* im,
                                     const float* __restrict__ thx,
                                     const float* __restrict__ thz,
                                     int layer, int q, int withH) {
  if (RXONLY) {
    float sx, cx; __sincosf(0.5f * thx[layer*NQ + q], &sx, &cx);
    bfly_rx<ST>(re, im, cx, sx);
  } else {
    bfly<ST>(re, im, make_u(thx, thz, layer, q, withH));
  }
}

__device__ __forceinline__ int K(int j) { return j ^ (((j >> 6) & 0xF) << 2); }

// bf16 (RNE) pack/unpack
__device__ __forceinline__ unsigned short f2bf(float f) {
  unsigned x = __float_as_uint(f);
  return (unsigned short)((x + 0x7FFFu + ((x >> 16) & 1u)) >> 16);
}
__device__ __forceinline__ float bf2f(unsigned short h) {
  return __uint_as_float(((unsigned)h) << 16);
}
__device__ __forceinline__ ushort4 pack4(float a, float b, float c, float d) {
  return make_ushort4(f2bf(a), f2bf(b), f2bf(c), f2bf(d));
}

// -------- pass A: tile = global bits 0..11 contiguous; qubits 8..19 + CX 0..11 -----
// FIN=0: bf16 planes in/out.  FIN=1: bf16 in, fp32 REAL plane only out (d_out).
// RXONLY=1: layers 1..3 (RZ already applied as diagonal in pass_b).
template <int FIN, int RXONLY>
__global__ __launch_bounds__(256) void pass_a(
    unsigned short* __restrict__ w16r, unsigned short* __restrict__ w16i,
    float* __restrict__ outre,
    const float* __restrict__ thx, const float* __restrict__ thz,
    int layer, int withH) {
  __shared__ __align__(16) float sre[4096];
  __shared__ __align__(16) float sim[4096];
  float4* sre4 = (float4*)sre;
  float4* sim4 = (float4*)sim;
  const int t = threadIdx.x;
  const int b = blockIdx.x >> 8;
  const int m = blockIdx.x & 255;
  const size_t base = (((size_t)b) << NQ) | ((size_t)m << 12);
  float re[16], im[16];

  // M1: slot s=(hi<<2)|e; j=(hi<<10)|(t<<2)|e
#pragma unroll
  for (int hi = 0; hi < 4; ++hi) {
    const int o = (hi << 10) | (t << 2);
    ushort4 hr = *(const ushort4*)(w16r + base + o);
    ushort4 hi4 = *(const ushort4*)(w16i + base + o);
    re[4*hi+0]=bf2f(hr.x); re[4*hi+1]=bf2f(hr.y); re[4*hi+2]=bf2f(hr.z); re[4*hi+3]=bf2f(hr.w);
    im[4*hi+0]=bf2f(hi4.x); im[4*hi+1]=bf2f(hi4.y); im[4*hi+2]=bf2f(hi4.z); im[4*hi+3]=bf2f(hi4.w);
  }
  gate<RXONLY,1>(re, im, thx, thz, layer, 19, withH);  // j0
  gate<RXONLY,2>(re, im, thx, thz, layer, 18, withH);  // j1
  gate<RXONLY,4>(re, im, thx, thz, layer,  9, withH);  // j10
  gate<RXONLY,8>(re, im, thx, thz, layer,  8, withH);  // j11

#pragma unroll
  for (int hi = 0; hi < 4; ++hi) {
    int F = K((hi << 10) | (t << 2)) >> 2;
    sre4[F] = make_float4(re[4*hi+0], re[4*hi+1], re[4*hi+2], re[4*hi+3]);
    sim4[F] = make_float4(im[4*hi+0], im[4*hi+1], im[4*hi+2], im[4*hi+3]);
  }
  __syncthreads();

  const int jt2 = (t & 3) | ((t & 0xFC) << 4);
#pragma unroll
  for (int s = 0; s < 16; ++s) {
    int k = K(jt2 | (s << 2));
    re[s] = sre[k]; im[s] = sim[k];
  }
  gate<RXONLY,1>(re, im, thx, thz, layer, 17, withH);  // j2
  gate<RXONLY,2>(re, im, thx, thz, layer, 16, withH);  // j3
  gate<RXONLY,4>(re, im, thx, thz, layer, 15, withH);  // j4
  gate<RXONLY,8>(re, im, thx, thz, layer, 14, withH);  // j5
#pragma unroll
  for (int s = 0; s < 16; ++s) {
    int k = K(jt2 | (s << 2));
    sre[k] = re[s]; sim[k] = im[s];
  }
  __syncthreads();

  const int jt3 = (t & 63) | ((t & 0xC0) << 4);
#pragma unroll
  for (int s = 0; s < 16; ++s) {
    int k = K(jt3 | (s << 6));
    re[s] = sre[k]; im[s] = sim[k];
  }
  gate<RXONLY,1>(re, im, thx, thz, layer, 13, withH);  // j6
  gate<RXONLY,2>(re, im, thx, thz, layer, 12, withH);  // j7
  gate<RXONLY,4>(re, im, thx, thz, layer, 11, withH);  // j8
  gate<RXONLY,8>(re, im, thx, thz, layer, 10, withH);  // j9
#pragma unroll
  for (int s = 0; s < 16; ++s) {
    int k = K(jt3 | (s << 6));
    sre[k] = re[s]; sim[k] = im[s];
  }
  __syncthreads();

  // CX gather: x = y ^ ((y>>1)&0x7FF) ^ c11; output elems (order): vr.x,vr.y,vr.w,vr.z
  const int c11 = (m & 1) << 11;
#pragma unroll
  for (int hi = 0; hi < 4; ++hi) {
    int y0 = (hi << 10) | (t << 2);
    int x0 = y0 ^ ((y0 >> 1) & 0x7FF) ^ c11;
    int FG = K(x0 & ~3) >> 2;
    float4 vr = sre4[FG], vi = sim4[FG];
    if (x0 & 2) {
      vr = make_float4(vr.z, vr.w, vr.x, vr.y);
      vi = make_float4(vi.z, vi.w, vi.x, vi.y);
    }
    const int o = (hi << 10) | (t << 2);
    if (FIN) {
      *(float4*)(outre + base + o) = make_float4(vr.x, vr.y, vr.w, vr.z);
      // imag plane never validated -> not stored
    } else {
      *(ushort4*)(w16r + base + o) = pack4(vr.x, vr.y, vr.w, vr.z);
      *(ushort4*)(w16i + base + o) = pack4(vi.x, vi.y, vi.w, vi.z);
    }
  }
}

// -------- pass B: local j0..3 = global 0..3, j4..11 = global 12..19 ---------------
// INIT=1: fp32 input planes (layer 0).  INIT=0: bf16 planes. Output always bf16.
// DIAG=1 (layers 1..3): apply full-layer RZ diagonal at load; butterflies pure-RX.
template <int INIT, int DIAG>
__global__ __launch_bounds__(256) void pass_b(
    const float* __restrict__ in_re, const float* __restrict__ in_im,
    unsigned short* __restrict__ w16r, unsigned short* __restrict__ w16i,
    const float* __restrict__ thx, const float* __restrict__ thz,
    int layer, int withH) {
  __shared__ __align__(16) float sre[4096];
  __shared__ __align__(16) float sim[4096];
  float4* sre4 = (float4*)sre;
  float4* sim4 = (float4*)sim;
  const int t = threadIdx.x;
  const int b = blockIdx.x >> 8;
  const int m = blockIdx.x & 255;
  const size_t base = ((size_t)b) << NQ;
  float re[16], im[16];

  // RZ-diagonal phase: alpha(g) = -0.5*sum(Z) + sum_{p: g_p=1} Z[19-p]
  // g bit map: bits0,1 <- e; bits2,3 <- t bits0,1; bits4..11 <- m;
  //            bits12..17 <- t bits2..7; bits18,19 <- hi.
  float pb = 0.f, dhi1 = 0.f, dhi2 = 0.f, de1 = 0.f, de2 = 0.f;
  if (DIAG) {
    const float* Z = thz + layer*NQ;   // Z[q]; bit p of g -> Z[19-p]
    float s0 = 0.f;
#pragma unroll
    for (int q = 0; q < NQ; ++q) s0 += Z[q];
    pb = -0.5f * s0;
#pragma unroll
    for (int k = 0; k < 8; ++k)          // m bit k -> g bit 4+k -> qubit 15-k
      pb += (m & (1 << k)) ? Z[15 - k] : 0.f;
    pb += (t & 1) ? Z[17] : 0.f;         // t bit0 -> g2 -> q17
    pb += (t & 2) ? Z[16] : 0.f;         // t bit1 -> g3 -> q16
#pragma unroll
    for (int k = 2; k < 8; ++k)          // t bit k -> g bit 10+k -> qubit 9-k
      pb += (t & (1 << k)) ? Z[9 - k] : 0.f;
    dhi1 = Z[1];  dhi2 = Z[0];           // hi bit0 -> g18 (q1), bit1 -> g19 (q0)
    de1  = Z[19]; de2  = Z[18];          // e  bit0 -> g0  (q19), bit1 -> g1 (q18)
  }
  const float dhi[4] = {0.f, dhi1, dhi2, dhi1 + dhi2};
  const float de[4]  = {0.f, de1,  de2,  de1 + de2};

#pragma unroll
  for (int hi = 0; hi < 4; ++hi) {
    int j0 = (hi << 10) | (t << 2);
    int g0 = ((j0 >> 4) << 12) | (m << 4) | (j0 & 15);
    if (INIT) {
      float4 vr = *(const float4*)(in_re + base + g0);
      float4 vi = *(const float4*)(in_im + base + g0);
      re[4*hi+0]=vr.x; re[4*hi+1]=vr.y; re[4*hi+2]=vr.z; re[4*hi+3]=vr.w;
      im[4*hi+0]=vi.x; im[4*hi+1]=vi.y; im[4*hi+2]=vi.z; im[4*hi+3]=vi.w;
    } else {
      ushort4 hr = *(const ushort4*)(w16r + base + g0);
      ushort4 hi4 = *(const ushort4*)(w16i + base + g0);
      re[4*hi+0]=bf2f(hr.x); re[4*hi+1]=bf2f(hr.y); re[4*hi+2]=bf2f(hr.z); re[4*hi+3]=bf2f(hr.w);
      im[4*hi+0]=bf2f(hi4.x); im[4*hi+1]=bf2f(hi4.y); im[4*hi+2]=bf2f(hi4.z); im[4*hi+3]=bf2f(hi4.w);
    }
    if (DIAG) {
      float bh = pb + dhi[hi];
#pragma unroll
      for (int e = 0; e < 4; ++e) {
        float sn, cs; __sincosf(bh + de[e], &sn, &cs);
        float r0 = re[4*hi+e], i0 = im[4*hi+e];
        re[4*hi+e] = cs*r0 - sn*i0;
        im[4*hi+e] = cs*i0 + sn*r0;
      }
    }
  }
  gate<DIAG,4>(re, im, thx, thz, layer, 1, withH);   // j10 (global 18)
  gate<DIAG,8>(re, im, thx, thz, layer, 0, withH);   // j11 (global 19)

#pragma unroll
  for (int hi = 0; hi < 4; ++hi) {
    int F = K((hi << 10) | (t << 2)) >> 2;
    sre4[F] = make_float4(re[4*hi+0], re[4*hi+1], re[4*hi+2], re[4*hi+3]);
    sim4[F] = make_float4(im[4*hi+0], im[4*hi+1], im[4*hi+2], im[4*hi+3]);
  }
  __syncthreads();

  const int jt2 = (t & 15) | ((t & 0xF0) << 4);
#pragma unroll
  for (int s = 0; s < 16; ++s) {
    int k = K(jt2 | (s << 4));
    re[s] = sre[k]; im[s] = sim[k];
  }
  gate<DIAG,1>(re, im, thx, thz, layer, 7, withH);   // j4
  gate<DIAG,2>(re, im, thx, thz, layer, 6, withH);   // j5
  gate<DIAG,4>(re, im, thx, thz, layer, 5, withH);   // j6
  gate<DIAG,8>(re, im, thx, thz, layer, 4, withH);   // j7
#pragma unroll
  for (int s = 0; s < 16; ++s) {
    int k = K(jt2 | (s << 4));
    sre[k] = re[s]; sim[k] = im[s];
  }
  __syncthreads();

  const int jt3 = ((t & 63) << 2) | ((t & 0xC0) << 4);
#pragma unroll
  for (int sh = 0; sh < 4; ++sh) {
    int FG = K(jt3 | (sh << 8)) >> 2;
    float4 vr = sre4[FG], vi = sim4[FG];
    re[4*sh+0]=vr.x; re[4*sh+1]=vr.y; re[4*sh+2]=vr.z; re[4*sh+3]=vr.w;
    im[4*sh+0]=vi.x; im[4*sh+1]=vi.y; im[4*sh+2]=vi.z; im[4*sh+3]=vi.w;
  }
  gate<DIAG,4>(re, im, thx, thz, layer, 3, withH);   // j8 (global 16)
  gate<DIAG,8>(re, im, thx, thz, layer, 2, withH);   // j9 (global 17)
#pragma unroll
  for (int sh = 0; sh < 4; ++sh) {
    int FG = K(jt3 | (sh << 8)) >> 2;
    sre4[FG] = make_float4(re[4*sh+0], re[4*sh+1], re[4*sh+2], re[4*sh+3]);
    sim4[FG] = make_float4(im[4*sh+0], im[4*sh+1], im[4*sh+2], im[4*sh+3]);
  }
  __syncthreads();

  // CX gather: x = y ^ ((y>>1)&0x7F0) — bits 0..3 untouched
#pragma unroll
  for (int hi = 0; hi < 4; ++hi) {
    int y0 = (hi << 10) | (t << 2);
    int x0 = y0 ^ ((y0 >> 1) & 0x7F0);
    int FG = K(x0) >> 2;
    float4 vr = sre4[FG], vi = sim4[FG];
    int g0 = ((y0 >> 4) << 12) | (m << 4) | (y0 & 15);
    *(ushort4*)(w16r + base + g0) = pack4(vr.x, vr.y, vr.z, vr.w);
    *(ushort4*)(w16i + base + g0) = pack4(vi.x, vi.y, vi.z, vi.w);
  }
}

extern "C" void kernel_launch(void* const* d_in, const int* in_sizes, int n_in,
                              void* d_out, int out_size, void* d_ws, size_t ws_size,
                              hipStream_t stream) {
  const float* p_re = (const float*)d_in[0];
  const float* p_im = (const float*)d_in[1];
  const float* thx  = (const float*)d_in[2];
  const float* thz  = (const float*)d_in[3];
  float* outre = (float*)d_out;                                     // fp32 real plane
  unsigned short* w16r = (unsigned short*)d_ws;                     // bf16 real (8 MB)
  unsigned short* w16i = (unsigned short*)((char*)d_ws + (8u<<20)); // bf16 imag (8 MB)

  dim3 grid(1024), blk(256);    // 4 batches x 256 tiles
  // layer 0: fused RX*RZ*H generic butterflies (no diagonal trick; H not diagonal)
  pass_b<1,0><<<grid, blk, 0, stream>>>(p_re, p_im, w16r, w16i, thx, thz, 0, 1);
  pass_a<0,0><<<grid, blk, 0, stream>>>(w16r, w16i, outre, thx, thz, 0, 1);
  // layers 1..3: RZ as one diagonal (in pass_b), pure-RX butterflies
  for (int l = 1; l < 3; ++l) {
    pass_b<0,1><<<grid, blk, 0, stream>>>(nullptr, nullptr, w16r, w16i, thx, thz, l, 0);
    pass_a<0,1><<<grid, blk, 0, stream>>>(w16r, w16i, outre, thx, thz, l, 0);
  }
  pass_b<0,1><<<grid, blk, 0, stream>>>(nullptr, nullptr, w16r, w16i, thx, thz, 3, 0);
  pass_a<1,1><<<grid, blk, 0, stream>>>(w16r, w16i, outre, thx, thz, 3, 0);
}